// Round 1
// baseline (409.724 us; speedup 1.0000x reference)
//
#include <hip/hip_runtime.h>
#include <math.h>

// ---------------- CSR build ----------------

__global__ void k_init(float* deg, int* counts, int* cursor, int n) {
    int i = blockIdx.x * blockDim.x + threadIdx.x;
    if (i < n) { deg[i] = 1.0f; counts[i] = 0; cursor[i] = 0; }
}

__global__ void k_hist(const int* __restrict__ col, const float* __restrict__ w,
                       float* __restrict__ deg, int* __restrict__ counts, int e) {
    int i = blockIdx.x * blockDim.x + threadIdx.x;
    if (i < e) {
        int c = col[i];
        atomicAdd(&deg[c], w[i]);
        atomicAdd(&counts[c], 1);
    }
}

__global__ void k_scan1(const int* __restrict__ counts, int* __restrict__ rowptr,
                        int* __restrict__ bsum, int n) {
    __shared__ int s[256];
    int t = threadIdx.x;
    int i = blockIdx.x * 256 + t;
    int v = (i < n) ? counts[i] : 0;
    s[t] = v; __syncthreads();
    for (int off = 1; off < 256; off <<= 1) {
        int a = s[t];
        int b = (t >= off) ? s[t - off] : 0;
        __syncthreads();
        s[t] = a + b;
        __syncthreads();
    }
    if (i < n) rowptr[i + 1] = s[t];
    if (t == 255) bsum[blockIdx.x] = s[255];
}

__global__ void k_scan2(int* __restrict__ bsum, int nb) {
    // in-place exclusive scan (nb <= 256)
    __shared__ int s[256];
    int t = threadIdx.x;
    int v = (t < nb) ? bsum[t] : 0;
    s[t] = v; __syncthreads();
    for (int off = 1; off < 256; off <<= 1) {
        int a = s[t];
        int b = (t >= off) ? s[t - off] : 0;
        __syncthreads();
        s[t] = a + b;
        __syncthreads();
    }
    if (t < nb) bsum[t] = s[t] - v;  // exclusive
}

__global__ void k_scan3(int* __restrict__ rowptr, const int* __restrict__ bsum, int n) {
    int i = blockIdx.x * 256 + threadIdx.x;
    if (i < n) rowptr[i + 1] += bsum[blockIdx.x];
    if (i == 0) rowptr[0] = 0;
}

__global__ void k_rsqrt(float* deg, int n) {
    int i = blockIdx.x * blockDim.x + threadIdx.x;
    if (i < n) {
        float d = deg[i];
        deg[i] = (d > 0.f) ? rsqrtf(fmaxf(d, 1e-30f)) : 0.f;
    }
}

__global__ void k_scatter(const int* __restrict__ row, const int* __restrict__ col,
                          const float* __restrict__ w, const int* __restrict__ rowptr,
                          int* __restrict__ cursor, int2* __restrict__ edges, int e) {
    int i = blockIdx.x * blockDim.x + threadIdx.x;
    if (i < e) {
        int c = col[i];
        int p = rowptr[c] + atomicAdd(&cursor[c], 1);
        edges[p] = make_int2(row[i], __float_as_int(w[i]));
    }
}

// ---------------- GEMM: out[i,:] = dis[i] * (A[i,:] @ W)  (W is K x 128) ----------------

template<int K>
__global__ __launch_bounds__(256) void k_gemm_scale(
    const float* __restrict__ A, const float* __restrict__ W,
    const float* __restrict__ dis, float* __restrict__ out, int n)
{
    constexpr int KC = 32;
    __shared__ __align__(16) float Wl[KC][128];
    __shared__ float Al[64][KC + 1];
    const int tid = threadIdx.x;
    const int tx = tid & 31, ty = tid >> 5;
    const int row0 = blockIdx.x * 64;
    float4 acc[8];
#pragma unroll
    for (int r = 0; r < 8; ++r) acc[r] = make_float4(0.f, 0.f, 0.f, 0.f);

    for (int kc = 0; kc < K; kc += KC) {
        // stage W chunk [KC][128]
#pragma unroll
        for (int j = 0; j < (KC * 128) / 256; ++j) {
            int idx = tid + 256 * j;
            int r = idx >> 7, c = idx & 127;
            Wl[r][c] = W[(size_t)(kc + r) * 128 + c];
        }
        // stage A tile [64][KC]
#pragma unroll
        for (int j = 0; j < (64 * KC) / 256; ++j) {
            int idx = tid + 256 * j;
            int r = idx >> 5, c = idx & 31;
            int gr = row0 + r;
            Al[r][c] = (gr < n) ? A[(size_t)gr * K + kc + c] : 0.f;
        }
        __syncthreads();
#pragma unroll
        for (int j = 0; j < KC; ++j) {
            float4 bv = *reinterpret_cast<const float4*>(&Wl[j][tx * 4]);
#pragma unroll
            for (int ri = 0; ri < 8; ++ri) {
                float av = Al[ty * 8 + ri][j];
                acc[ri].x = fmaf(av, bv.x, acc[ri].x);
                acc[ri].y = fmaf(av, bv.y, acc[ri].y);
                acc[ri].z = fmaf(av, bv.z, acc[ri].z);
                acc[ri].w = fmaf(av, bv.w, acc[ri].w);
            }
        }
        __syncthreads();
    }
#pragma unroll
    for (int ri = 0; ri < 8; ++ri) {
        int gr = row0 + ty * 8 + ri;
        if (gr < n) {
            float s = dis[gr];
            float4 v = acc[ri];
            v.x *= s; v.y *= s; v.z *= s; v.w *= s;
            *reinterpret_cast<float4*>(&out[(size_t)gr * 128 + tx * 4]) = v;
        }
    }
}

// ---------------- edge aggregation: out[c,:] = relu(dis[c]*(hs[c,:] + sum w*hs[src,:]) + b) ----------------

__global__ __launch_bounds__(256) void k_agg(
    const float* __restrict__ hs, const int2* __restrict__ edges,
    const int* __restrict__ rowptr, const float* __restrict__ dis,
    const float* __restrict__ bias, float* __restrict__ out, int n)
{
    int t = blockIdx.x * blockDim.x + threadIdx.x;
    int node = t >> 5, lane = t & 31;
    if (node >= n) return;
    int c4 = lane * 4;
    float4 acc = *reinterpret_cast<const float4*>(&hs[(size_t)node * 128 + c4]);
    int beg = rowptr[node], end = rowptr[node + 1];
    for (int p = beg; p < end; ++p) {
        int2 rec = edges[p];
        float w = __int_as_float(rec.y);
        float4 v = *reinterpret_cast<const float4*>(&hs[(size_t)rec.x * 128 + c4]);
        acc.x = fmaf(w, v.x, acc.x);
        acc.y = fmaf(w, v.y, acc.y);
        acc.z = fmaf(w, v.z, acc.z);
        acc.w = fmaf(w, v.w, acc.w);
    }
    float s = dis[node];
    float4 b = *reinterpret_cast<const float4*>(&bias[c4]);
    float4 o;
    o.x = fmaxf(fmaf(s, acc.x, b.x), 0.f);
    o.y = fmaxf(fmaf(s, acc.y, b.y), 0.f);
    o.z = fmaxf(fmaf(s, acc.z, b.z), 0.f);
    o.w = fmaxf(fmaf(s, acc.w, b.w), 0.f);
    *reinterpret_cast<float4*>(&out[(size_t)node * 128 + c4]) = o;
}

// ---------------- pooling: hg[g] = [max over nodes, mean over nodes, rho[g]] ----------------

__device__ __forceinline__ int lowbound(const int* __restrict__ b, int n, int key) {
    int lo = 0, hi = n;
    while (lo < hi) { int mid = (lo + hi) >> 1; if (b[mid] < key) lo = mid + 1; else hi = mid; }
    return lo;
}

__global__ void k_pool(const float* __restrict__ h, const int* __restrict__ batch,
                       const float* __restrict__ rho, float* __restrict__ hg, int n)
{
    int g = blockIdx.x;
    int ch = threadIdx.x;   // 0..127
    __shared__ int sbeg, send;
    if (ch == 0) {
        sbeg = lowbound(batch, n, g);
        send = lowbound(batch, n, g + 1);
    }
    __syncthreads();
    int beg = sbeg, end = send;
    float mx = -INFINITY, sm = 0.f;
    for (int i = beg; i < end; ++i) {
        float v = h[(size_t)i * 128 + ch];
        mx = fmaxf(mx, v);
        sm += v;
    }
    float cnt = (float)(end - beg);
    hg[(size_t)g * 257 + ch] = mx;
    hg[(size_t)g * 257 + 128 + ch] = sm / cnt;
    if (ch == 0) hg[(size_t)g * 257 + 256] = rho[g];
}

// ---------------- small dense layers: one block per graph row ----------------

template<int KF>
__global__ void k_mlp(const float* __restrict__ in, const float* __restrict__ W,
                      const float* __restrict__ b, float* __restrict__ out,
                      int outf, int relu)
{
    int g = blockIdx.x;
    __shared__ float row[KF];
    for (int j = threadIdx.x; j < KF; j += blockDim.x) row[j] = in[(size_t)g * KF + j];
    __syncthreads();
    for (int k = threadIdx.x; k < outf; k += blockDim.x) {
        float acc = b[k];
        for (int j = 0; j < KF; ++j) acc = fmaf(row[j], W[(size_t)j * outf + k], acc);
        if (relu) acc = fmaxf(acc, 0.f);
        out[(size_t)g * outf + k] = acc;
    }
}

// ---------------- launch ----------------

extern "C" void kernel_launch(void* const* d_in, const int* in_sizes, int n_in,
                              void* d_out, int out_size, void* d_ws, size_t ws_size,
                              hipStream_t stream)
{
    const float* x        = (const float*)d_in[0];
    const float* edge_attr= (const float*)d_in[1];
    const float* rho      = (const float*)d_in[2];
    const float* conv0_w  = (const float*)d_in[3];
    const float* conv0_b  = (const float*)d_in[4];
    const float* conv1_w  = (const float*)d_in[5];
    const float* conv1_b  = (const float*)d_in[6];
    const float* mlp0_w   = (const float*)d_in[7];
    const float* mlp0_b   = (const float*)d_in[8];
    const float* mlp1_w   = (const float*)d_in[9];
    const float* mlp1_b   = (const float*)d_in[10];
    const float* out_w    = (const float*)d_in[11];
    const float* out_b    = (const float*)d_in[12];
    const int*   edge_idx = (const int*)d_in[13];
    const int*   batch    = (const int*)d_in[14];

    const int N = in_sizes[0] / 64;
    const int E = in_sizes[1];
    const int G = in_sizes[2];
    const int* erow = edge_idx;
    const int* ecol = edge_idx + E;

    char* ws = (char*)d_ws;
    size_t off = 0;
    auto alloc = [&](size_t bytes) -> void* {
        off = (off + 255) & ~(size_t)255;
        void* p = ws + off;
        off += bytes;
        return p;
    };
    float* deg    = (float*)alloc((size_t)N * 4);        // becomes dis after k_rsqrt
    int*   counts = (int*)  alloc((size_t)N * 4);
    int*   cursor = (int*)  alloc((size_t)N * 4);
    int*   rowptr = (int*)  alloc((size_t)(N + 1) * 4);
    int NB = (N + 255) / 256;
    int*   bsum   = (int*)  alloc((size_t)NB * 4);
    int2*  edges  = (int2*) alloc((size_t)E * 8);
    float* bufA   = (float*)alloc((size_t)N * 128 * 4);
    float* bufB   = (float*)alloc((size_t)N * 128 * 4);
    float* hg     = (float*)alloc((size_t)G * 257 * 4);
    float* t0     = (float*)alloc((size_t)G * 128 * 4);
    float* t1     = (float*)alloc((size_t)G * 128 * 4);

    dim3 b256(256);
    k_init<<<(N + 255) / 256, b256, 0, stream>>>(deg, counts, cursor, N);
    k_hist<<<(E + 255) / 256, b256, 0, stream>>>(ecol, edge_attr, deg, counts, E);
    k_scan1<<<NB, b256, 0, stream>>>(counts, rowptr, bsum, N);
    k_scan2<<<1, b256, 0, stream>>>(bsum, NB);
    k_scan3<<<NB, b256, 0, stream>>>(rowptr, bsum, N);
    k_rsqrt<<<(N + 255) / 256, b256, 0, stream>>>(deg, N);
    k_scatter<<<(E + 255) / 256, b256, 0, stream>>>(erow, ecol, edge_attr, rowptr, cursor, edges, E);

    // layer 0: hs0 = (x @ W0) * dis ; h0 = relu(dis*(hs0 + sum) + b0)
    k_gemm_scale<64><<<(N + 63) / 64, b256, 0, stream>>>(x, conv0_w, deg, bufA, N);
    k_agg<<<((size_t)N * 32 + 255) / 256, b256, 0, stream>>>(bufA, edges, rowptr, deg, conv0_b, bufB, N);
    // layer 1
    k_gemm_scale<128><<<(N + 63) / 64, b256, 0, stream>>>(bufB, conv1_w, deg, bufA, N);
    k_agg<<<((size_t)N * 32 + 255) / 256, b256, 0, stream>>>(bufA, edges, rowptr, deg, conv1_b, bufB, N);

    // pooling + MLP head
    k_pool<<<G, dim3(128), 0, stream>>>(bufB, batch, rho, hg, N);
    k_mlp<257><<<G, dim3(128), 0, stream>>>(hg, mlp0_w, mlp0_b, t0, 128, 1);
    k_mlp<128><<<G, dim3(128), 0, stream>>>(t0, mlp1_w, mlp1_b, t1, 128, 1);
    k_mlp<128><<<G, dim3(128), 0, stream>>>(t1, out_w, out_b, (float*)d_out, 36, 0);
}